// Round 1
// baseline (99.206 us; speedup 1.0000x reference)
//
#include <hip/hip_runtime.h>
#include <math.h>

#define ROWS_TOTAL 8192
#define KDIM 4096
#define NJ 25      // 4 pre + 4 post + 16 res + 1 ssq
#define RPB 64     // rows per block (one per lane)
#define KQ 1024    // k-range per block (quarter)
#define KC 64      // k per staged chunk

// ------------------------------------------------------------------
// Kernel 1: partial dot products.
// grid = 512 blocks: 128 row-groups x 4 k-quarters. 256 threads (4 waves).
// Within a chunk of 64 k's, wave w handles quads (4 consecutive k) with
// quad_index % 4 == w, so k is wave-uniform -> phi/rmsw via s_load.
// x chunk staged in LDS as [quad(16)][row(64)] float4 (conflict-free b128).
// ws layout: ws[quarter][j(25)][row(8192)]
// ------------------------------------------------------------------
__global__ __launch_bounds__(256) void mhc_main(
    const float* __restrict__ x,
    const float* __restrict__ rmsw,
    const float* __restrict__ phi_pre,
    const float* __restrict__ phi_post,
    const float* __restrict__ phi_res,
    float* __restrict__ ws)
{
    __shared__ __align__(16) float lds[4800];   // 16KB chunk area, reused for combine (4800 floats)
    const int bid  = blockIdx.x;
    const int g    = bid >> 2;   // row group 0..127
    const int q    = bid & 3;    // k quarter 0..3
    const int t    = threadIdx.x;
    const int wave = __builtin_amdgcn_readfirstlane(t >> 6);
    const int lane = t & 63;

    float accp[4] = {0.f, 0.f, 0.f, 0.f};
    float acco[4] = {0.f, 0.f, 0.f, 0.f};
    float accr[16] = {0.f};
    float ssq = 0.f;

    const int rloc = t >> 4;     // 0..15 (staging row slot)
    const int qloc = t & 15;     // 0..15 (staging quad slot)
    const float* xg = x + (size_t)(g * RPB) * KDIM + q * KQ;

    for (int c = 0; c < KQ / KC; ++c) {
        const int kbase = c * KC;
        __syncthreads();   // previous chunk fully consumed before overwrite
        // stage: 64 rows x 64 k, coalesced 256B segments per 16 lanes
        #pragma unroll
        for (int i = 0; i < 4; ++i) {
            const int row = rloc + 16 * i;
            const float4 v = *(const float4*)(xg + (size_t)row * KDIM + kbase + qloc * 4);
            ((float4*)lds)[qloc * 64 + row] = v;
        }
        __syncthreads();
        #pragma unroll
        for (int qq = 0; qq < 4; ++qq) {
            const int qd = wave + qq * 4;                 // quad 0..15, wave-uniform
            const float4 xv = ((const float4*)lds)[qd * 64 + lane];
            const int kk = q * KQ + kbase + qd * 4;       // global k of xv.x (scalar)
            const float4 wv = *(const float4*)(rmsw + kk);
            float xa[4] = {xv.x, xv.y, xv.z, xv.w};
            float wa[4] = {wv.x, wv.y, wv.z, wv.w};
            #pragma unroll
            for (int j = 0; j < 4; ++j) {
                const float xj = xa[j];
                const float xw = xj * wa[j];
                ssq = fmaf(xj, xj, ssq);
                const float4 pp = ((const float4*)phi_pre)[kk + j];
                accp[0] = fmaf(xw, pp.x, accp[0]);
                accp[1] = fmaf(xw, pp.y, accp[1]);
                accp[2] = fmaf(xw, pp.z, accp[2]);
                accp[3] = fmaf(xw, pp.w, accp[3]);
                const float4 po = ((const float4*)phi_post)[kk + j];
                acco[0] = fmaf(xw, po.x, acco[0]);
                acco[1] = fmaf(xw, po.y, acco[1]);
                acco[2] = fmaf(xw, po.z, acco[2]);
                acco[3] = fmaf(xw, po.w, acco[3]);
                #pragma unroll
                for (int ii = 0; ii < 4; ++ii) {
                    const float4 rr = ((const float4*)phi_res)[(kk + j) * 4 + ii];
                    accr[ii * 4 + 0] = fmaf(xw, rr.x, accr[ii * 4 + 0]);
                    accr[ii * 4 + 1] = fmaf(xw, rr.y, accr[ii * 4 + 1]);
                    accr[ii * 4 + 2] = fmaf(xw, rr.z, accr[ii * 4 + 2]);
                    accr[ii * 4 + 3] = fmaf(xw, rr.w, accr[ii * 4 + 3]);
                }
            }
        }
    }

    __syncthreads();
    // cross-wave combine in LDS: waves 1..3 dump, wave 0 sums and writes ws
    if (wave) {
        float* dst = lds + (wave - 1) * (64 * NJ);
        #pragma unroll
        for (int j = 0; j < 4; ++j)  dst[j * 64 + lane] = accp[j];
        #pragma unroll
        for (int j = 0; j < 4; ++j)  dst[(4 + j) * 64 + lane] = acco[j];
        #pragma unroll
        for (int j = 0; j < 16; ++j) dst[(8 + j) * 64 + lane] = accr[j];
        dst[24 * 64 + lane] = ssq;
    }
    __syncthreads();
    if (wave == 0) {
        float vals[NJ];
        #pragma unroll
        for (int j = 0; j < 4; ++j)  vals[j] = accp[j];
        #pragma unroll
        for (int j = 0; j < 4; ++j)  vals[4 + j] = acco[j];
        #pragma unroll
        for (int j = 0; j < 16; ++j) vals[8 + j] = accr[j];
        vals[24] = ssq;
        #pragma unroll
        for (int j = 0; j < NJ; ++j) {
            const float s = vals[j]
                          + lds[j * 64 + lane]
                          + lds[1600 + j * 64 + lane]
                          + lds[3200 + j * 64 + lane];
            ws[(size_t)q * (NJ * ROWS_TOTAL) + (size_t)j * ROWS_TOTAL + g * RPB + lane] = s;
        }
    }
}

// ------------------------------------------------------------------
// Kernel 2: combine 4 k-quarter partials, RMS scale, sigmoids, Sinkhorn.
// One thread per row; 128 blocks x 64 threads.
// ------------------------------------------------------------------
__device__ __forceinline__ float sigmoidf_(float z) {
    return 1.f / (1.f + __expf(-z));
}

__global__ __launch_bounds__(64) void mhc_epi(
    const float* __restrict__ ws,
    const float* __restrict__ b_pre,
    const float* __restrict__ b_post,
    const float* __restrict__ b_res,
    const float* __restrict__ a_pre,
    const float* __restrict__ a_post,
    const float* __restrict__ a_res,
    float* __restrict__ out)
{
    const int r = blockIdx.x * 64 + threadIdx.x;   // 0..8191
    float d[NJ];
    #pragma unroll
    for (int j = 0; j < NJ; ++j) {
        float s = 0.f;
        #pragma unroll
        for (int qq = 0; qq < 4; ++qq)
            s += ws[(size_t)qq * (NJ * ROWS_TOTAL) + (size_t)j * ROWS_TOTAL + r];
        d[j] = s;
    }
    const float scale = rsqrtf(d[24] * (1.0f / KDIM) + 1e-6f);
    const float ap  = a_pre[0] * scale;
    const float apo = a_post[0] * scale;
    const float ar  = a_res[0] * scale;

    float4 o0, o1;
    o0.x = sigmoidf_(fmaf(ap, d[0], b_pre[0]));
    o0.y = sigmoidf_(fmaf(ap, d[1], b_pre[1]));
    o0.z = sigmoidf_(fmaf(ap, d[2], b_pre[2]));
    o0.w = sigmoidf_(fmaf(ap, d[3], b_pre[3]));
    o1.x = 2.f * sigmoidf_(fmaf(apo, d[4], b_post[0]));
    o1.y = 2.f * sigmoidf_(fmaf(apo, d[5], b_post[1]));
    o1.z = 2.f * sigmoidf_(fmaf(apo, d[6], b_post[2]));
    o1.w = 2.f * sigmoidf_(fmaf(apo, d[7], b_post[3]));

    float m[16];
    #pragma unroll
    for (int i = 0; i < 16; ++i)
        m[i] = __expf(fmaf(ar, d[8 + i], b_res[i]));

    for (int it = 0; it < 20; ++it) {
        #pragma unroll
        for (int i = 0; i < 4; ++i) {           // row normalize
            const float s = m[4*i] + m[4*i+1] + m[4*i+2] + m[4*i+3];
            const float inv = 1.f / s;
            m[4*i] *= inv; m[4*i+1] *= inv; m[4*i+2] *= inv; m[4*i+3] *= inv;
        }
        #pragma unroll
        for (int i = 0; i < 4; ++i) {           // col normalize
            const float s = m[i] + m[4+i] + m[8+i] + m[12+i];
            const float inv = 1.f / s;
            m[i] *= inv; m[4+i] *= inv; m[8+i] *= inv; m[12+i] *= inv;
        }
    }

    float* o_pre  = out;
    float* o_post = out + 32768;
    float* o_res  = out + 65536;
    ((float4*)o_pre)[r]  = o0;
    ((float4*)o_post)[r] = o1;
    #pragma unroll
    for (int i = 0; i < 4; ++i)
        ((float4*)o_res)[r * 4 + i] = make_float4(m[4*i], m[4*i+1], m[4*i+2], m[4*i+3]);
}

extern "C" void kernel_launch(void* const* d_in, const int* in_sizes, int n_in,
                              void* d_out, int out_size, void* d_ws, size_t ws_size,
                              hipStream_t stream) {
    const float* x      = (const float*)d_in[0];
    const float* rmsw   = (const float*)d_in[1];
    const float* ppre   = (const float*)d_in[2];
    const float* ppost  = (const float*)d_in[3];
    const float* pres   = (const float*)d_in[4];
    const float* b_pre  = (const float*)d_in[5];
    const float* b_post = (const float*)d_in[6];
    const float* b_res  = (const float*)d_in[7];
    const float* a_pre  = (const float*)d_in[8];
    const float* a_post = (const float*)d_in[9];
    const float* a_res  = (const float*)d_in[10];
    float* ws  = (float*)d_ws;    // needs 4 * 25 * 8192 * 4 = 3.3 MB
    float* out = (float*)d_out;

    hipLaunchKernelGGL(mhc_main, dim3(512), dim3(256), 0, stream,
                       x, rmsw, ppre, ppost, pres, ws);
    hipLaunchKernelGGL(mhc_epi, dim3(128), dim3(64), 0, stream,
                       ws, b_pre, b_post, b_res, a_pre, a_post, a_res, out);
}